// Round 2
// baseline (262.018 us; speedup 1.0000x reference)
//
#include <hip/hip_runtime.h>

#define NUM_BINS 128
#define BATCH 128
#define HW (512 * 512)                 // elements per image
#define HBLOCKS_PER_IMG 32             // hist blocks per image
#define HIST_THREADS 256
#define NUM_WAVES (HIST_THREADS / 64)
#define HELEMS (HW / HBLOCKS_PER_IMG)  // 8192 elems per hist block
#define SBLOCKS_PER_IMG 16             // scale blocks per image
#define SCALE_THREADS 256
#define SELEMS (HW / SBLOCKS_PER_IMG)  // 16384 elems per scale block

typedef float f4 __attribute__((ext_vector_type(4)));

// ---------------------------------------------------------------------------
// Kernel 1: per-block partial histogram, torch.histc(min=0,max=1) semantics.
// Per-wave replicated LDS histograms; each block STORES its own partial
// (no global atomics, no pre-zeroing of the partial buffer needed).
// part layout: [b][blk][bin], bin contiguous.
// ---------------------------------------------------------------------------
__global__ __launch_bounds__(HIST_THREADS) void hist_kernel(
    const float* __restrict__ x, unsigned int* __restrict__ part) {
    __shared__ unsigned int lh[NUM_WAVES][NUM_BINS];

    const int tid  = threadIdx.x;
    const int wv   = tid >> 6;

    for (int i = tid; i < NUM_WAVES * NUM_BINS; i += HIST_THREADS)
        ((unsigned int*)lh)[i] = 0u;
    __syncthreads();

    const int b   = blockIdx.x >> 5;   // / HBLOCKS_PER_IMG
    const int blk = blockIdx.x & 31;
    const f4* xp = (const f4*)(x + (size_t)b * HW) + (size_t)blk * (HELEMS / 4);
    const int n4 = HELEMS / 4;         // 2048

    for (int i = tid; i < n4; i += HIST_THREADS) {
        f4 v = xp[i];
#pragma unroll
        for (int k = 0; k < 4; ++k) {
            float f = v[k];
            // (int) truncation == floor for f >= 0; f == 1.0 -> bin 127 via min
            int idx = min((int)(f * (float)NUM_BINS), NUM_BINS - 1);
            if (f >= 0.0f && f <= 1.0f) atomicAdd(&lh[wv][idx], 1u);
        }
    }
    __syncthreads();

    unsigned int* dst = part + (size_t)blockIdx.x * NUM_BINS;
    for (int i = tid; i < NUM_BINS; i += HIST_THREADS) {
        unsigned int s = 0u;
#pragma unroll
        for (int w = 0; w < NUM_WAVES; ++w) s += lh[w][i];
        dst[i] = s;   // plain store — no atomic, no memset dependency
    }
}

// ---------------------------------------------------------------------------
// Kernel 2 (fused): reduce partials -> tiny MLP -> out = x * w[b].
// Each block handles one image chunk; the per-image MLP is recomputed
// redundantly per block (sub-µs). Output stored nontemporally so the
// 134 MB write stream does not evict x from L3 (pass-2 x reads hit L3).
// ---------------------------------------------------------------------------
__global__ __launch_bounds__(SCALE_THREADS) void scale_kernel(
    const float* __restrict__ x, const unsigned int* __restrict__ part,
    const float* __restrict__ W1, const float* __restrict__ b1,
    const float* __restrict__ W2, const float* __restrict__ b2,
    float* __restrict__ out) {
    __shared__ float hist_s[NUM_BINS];
    __shared__ float w_s;

    const int tid = threadIdx.x;
    const int b   = blockIdx.x >> 4;   // / SBLOCKS_PER_IMG
    const int blk = blockIdx.x & 15;

    // 1) reduce the 32 partials for image b: thread t (<128) owns bin t
    if (tid < NUM_BINS) {
        const unsigned int* p = part + (size_t)b * HBLOCKS_PER_IMG * NUM_BINS + tid;
        unsigned int s = 0u;
#pragma unroll
        for (int j = 0; j < HBLOCKS_PER_IMG; ++j) s += p[j * NUM_BINS];
        hist_s[tid] = (float)s;        // exact: counts <= 262144 < 2^24
    }
    __syncthreads();

    // 2) MLP on wave 0, lanes 0..15 (one hidden unit each)
    float h = 0.0f;
    if (tid < 16) {
        float acc = b1[tid];
#pragma unroll 8
        for (int k = 0; k < NUM_BINS; ++k)
            acc = fmaf(hist_s[k], W1[k * 16 + tid], acc);
        h = fmaxf(acc, 0.0f) * W2[tid];
    }
    if (tid < 16) {
#pragma unroll
        for (int off = 8; off > 0; off >>= 1) h += __shfl_down(h, off);
        if (tid == 0) w_s = h + b2[0];
    }
    __syncthreads();

    // 3) scale this block's chunk
    const float s = w_s;
    const f4* xp = (const f4*)(x + (size_t)b * HW) + (size_t)blk * (SELEMS / 4);
    f4* op = (f4*)(out + (size_t)b * HW) + (size_t)blk * (SELEMS / 4);
    const int n4 = SELEMS / 4;         // 4096 -> 16 iters of float4 per thread
    for (int i = tid; i < n4; i += SCALE_THREADS) {
        f4 v = xp[i];
        f4 r = v * s;
        __builtin_nontemporal_store(r, &op[i]);
    }
}

extern "C" void kernel_launch(void* const* d_in, const int* in_sizes, int n_in,
                              void* d_out, int out_size, void* d_ws, size_t ws_size,
                              hipStream_t stream) {
    const float* x  = (const float*)d_in[0];
    const float* W1 = (const float*)d_in[1];
    const float* b1 = (const float*)d_in[2];
    const float* W2 = (const float*)d_in[3];
    const float* b2 = (const float*)d_in[4];
    float* out = (float*)d_out;

    // per-block partial histograms: 128 imgs * 32 blks * 128 bins * 4 B = 2 MiB
    unsigned int* part = (unsigned int*)d_ws;

    hist_kernel<<<BATCH * HBLOCKS_PER_IMG, HIST_THREADS, 0, stream>>>(x, part);
    scale_kernel<<<BATCH * SBLOCKS_PER_IMG, SCALE_THREADS, 0, stream>>>(
        x, part, W1, b1, W2, b2, out);
}